// Round 11
// baseline (188.670 us; speedup 1.0000x reference)
//
#include <hip/hip_runtime.h>
#include <stdint.h>
#include <stddef.h>
#include <math.h>

#define E_ 32
#define H_ 128
#define V_ 32000
#define NB 32
#define NT 128
#define NCONS 224      // consumer blocks (bid 32..255)
#define NCHUNK 250     // 128-col vocab chunks; 224 owned + 26 rotating extras
#define NX (NCHUNK - NCONS)   // 26 extra chunks
#define WSTEPS 16      // pipeline window (steps per release)
#define NWIN (NT / WSTEPS)    // 8 windows

typedef float f32x4 __attribute__((ext_vector_type(4)));
typedef short s16x8 __attribute__((ext_vector_type(8)));

__device__ inline unsigned short f2bf(float f) {
  uint32_t u = __float_as_uint(f);
  return (unsigned short)((u + 0x7FFFu + ((u >> 16) & 1u)) >> 16);
}

__device__ inline float dpp_xor1(float v) {   // lane l <- lane l^1 (quad_perm)
  return __int_as_float(__builtin_amdgcn_update_dpp(
      0, __float_as_int(v), 0xB1, 0xF, 0xF, true));
}
__device__ inline float dpp_xor2(float v) {   // lane l <- lane l^2
  return __int_as_float(__builtin_amdgcn_update_dpp(
      0, __float_as_int(v), 0x4E, 0xF, 0xF, true));
}

// Raw LDS-only barrier: s_waitcnt lgkmcnt(0) + s_barrier, NO vmcnt(0) drain.
// __syncthreads would emit s_waitcnt vmcnt(0) (full global-store drain) every
// step — the consumer's global stores must instead stay in flight and drain
// continuously at HBM rate.
__device__ inline void bar_lds() {
  __builtin_amdgcn_sched_barrier(0);
  asm volatile("s_waitcnt lgkmcnt(0)" ::: "memory");
  __builtin_amdgcn_s_barrier();
  __builtin_amdgcn_sched_barrier(0);
}

__global__ void zero_cnt(int* cnt) {
  if (threadIdx.x < NWIN) cnt[threadIdx.x] = 0;
}

// Fused producer-consumer, grid 256 x 512 (1 block/CU, all co-resident).
// Producer = R10 verbatim (measured win). Consumer: LDS-transposed epilogue
// (full 256B-contiguous store segments) + raw lgkm-only barriers.
__global__ __launch_bounds__(512, 1)
void lstm_fused(const float* __restrict__ x,
                const float* __restrict__ Wf, const float* __restrict__ bWf,
                const float* __restrict__ Uf, const float* __restrict__ bUf,
                const float* __restrict__ Wi, const float* __restrict__ bWi,
                const float* __restrict__ Ui, const float* __restrict__ bUi,
                const float* __restrict__ Wc, const float* __restrict__ bWc,
                const float* __restrict__ Uc, const float* __restrict__ bUc,
                const float* __restrict__ Wo, const float* __restrict__ bWo,
                const float* __restrict__ Uo, const float* __restrict__ bUo,
                const float* __restrict__ Vw, const float* __restrict__ Vb,
                unsigned short* __restrict__ hbf,  // [NT][NB][H_] bf16 bits
                int* __restrict__ cnt,             // [NWIN] window counters
                float* __restrict__ out,           // [NB][NT][V_]
                float* __restrict__ hlast)         // [NB][H_]
{
  __shared__ __align__(16) unsigned char smem[114688];
  const int bid = blockIdx.x;
  const int tid = threadIdx.x;

  if (bid < NB) {
    // ---------------- producer: recurrence for batch `bid` (R10 verbatim) ---
    float* xs = reinterpret_cast<float*>(smem);            // [NT][E_] 16 KB
    float* hd = reinterpret_cast<float*>(smem + 16384);    // [2][144] padded h

    const int q  = tid & 3;    // k-quarter
    const int jj = tid >> 2;   // output index 0..127

    const float* WL[4]  = {Wf, Wi, Wc, Wo};
    const float* UL[4]  = {Uf, Ui, Uc, Uo};
    const float* bWL[4] = {bWf, bWi, bWc, bWo};
    const float* bUL[4] = {bUf, bUi, bUc, bUo};

    f32x4 wr_[4][2];  // W[g][jj, 8q..8q+8)
    f32x4 ur_[4][8];  // U[g][jj, 32q..32q+32)  -- 160 VGPRs, MUST NOT SPILL
    float bias_[4];
#pragma unroll
    for (int g = 0; g < 4; ++g) {
      const f32x4* Wp = reinterpret_cast<const f32x4*>(WL[g] + jj * E_ + q * 8);
      wr_[g][0] = Wp[0]; wr_[g][1] = Wp[1];
      const f32x4* Up = reinterpret_cast<const f32x4*>(UL[g] + jj * H_ + q * 32);
#pragma unroll
      for (int r = 0; r < 8; ++r) ur_[g][r] = Up[r];
      bias_[g] = bWL[g][jj] + bUL[g][jj];
    }

    for (int i = tid; i < NT * E_; i += 512) xs[i] = x[bid * (NT * E_) + i];
    if (tid < 144) hd[tid] = 0.f;
    float creg = 0.f;
    __syncthreads();

    for (int t = 0; t < NT; ++t) {
      const int cur = t & 1, nxt = cur ^ 1;
      const f32x4* hq = reinterpret_cast<const f32x4*>(hd + cur * 144 + q * 36);
      const f32x4* xq = reinterpret_cast<const f32x4*>(xs + t * E_ + q * 8);

      f32x4 p0 = {0.f,0.f,0.f,0.f}, p1 = p0, p2 = p0, p3 = p0;
#pragma unroll
      for (int r = 0; r < 2; ++r) {
        f32x4 xv = xq[r];
        p0 += wr_[0][r] * xv; p1 += wr_[1][r] * xv;
        p2 += wr_[2][r] * xv; p3 += wr_[3][r] * xv;
      }
#pragma unroll
      for (int r = 0; r < 8; ++r) {
        f32x4 hv = hq[r];
        p0 += ur_[0][r] * hv; p1 += ur_[1][r] * hv;
        p2 += ur_[2][r] * hv; p3 += ur_[3][r] * hv;
      }
      float s0 = (p0.x + p0.y) + (p0.z + p0.w);
      float s1 = (p1.x + p1.y) + (p1.z + p1.w);
      float s2 = (p2.x + p2.y) + (p2.z + p2.w);
      float s3 = (p3.x + p3.y) + (p3.z + p3.w);
      s0 += dpp_xor1(s0); s0 += dpp_xor2(s0);
      s1 += dpp_xor1(s1); s1 += dpp_xor2(s1);
      s2 += dpp_xor1(s2); s2 += dpp_xor2(s2);
      s3 += dpp_xor1(s3); s3 += dpp_xor2(s3);
      s0 += bias_[0]; s1 += bias_[1]; s2 += bias_[2]; s3 += bias_[3];

      float own = (q == 0) ? s0 : (q == 1) ? s1 : (q == 2) ? s2 : s3;
      float xin = (q == 2) ? own + own : own;
      float val = __builtin_amdgcn_rcpf(1.f + __expf(-xin));
      if (q == 2) val = 2.f * val - 1.f;
      float v1 = dpp_xor1(val);
      float v2 = dpp_xor2(val);
      float v3 = dpp_xor2(v1);
      float f_ = (q == 0) ? val : (q == 1) ? v1 : (q == 2) ? v2 : v3;
      float i_ = (q == 0) ? v1 : (q == 1) ? val : (q == 2) ? v3 : v2;
      float c_ = (q == 0) ? v2 : (q == 1) ? v3 : (q == 2) ? val : v1;
      float o_ = (q == 0) ? v3 : (q == 1) ? v2 : (q == 2) ? v1 : val;

      float cn = f_ * creg + i_ * c_;
      creg = cn;
      float hn = o_ * (2.f * __builtin_amdgcn_rcpf(1.f + __expf(-2.f * cn)) - 1.f);

      if (q == 0) {
        hd[nxt * 144 + jj + ((jj >> 5) << 2)] = hn;
        hbf[((size_t)t * NB + bid) * H_ + jj] = f2bf(hn);  // [t][b][H]
        if (t == NT - 1) hlast[bid * H_ + jj] = hn;
      }
      __syncthreads();
      if ((t & (WSTEPS - 1)) == (WSTEPS - 1) && tid == 0)
        __hip_atomic_fetch_add(&cnt[t / WSTEPS], 1, __ATOMIC_RELEASE,
                               __HIP_MEMORY_SCOPE_AGENT);
    }
    return;
  }

  // ---------------- consumer: own chunk + rotating duty chunk ----------------
  const int cid = bid - NB;                       // 0..223, owns chunk `cid`
  unsigned char* vwo = smem;                      // own  Vw [128][256 B] swizzled
  unsigned char* vwx = smem + 32768;              // duty Vw [128][256 B] swizzled
  unsigned char* hlb = smem + 65536;              // [2][32 rows][256 B] swizzled
  float* trO = reinterpret_cast<float*>(smem + 81920);  // [32][128] f32, 16 KB
  float* trX = reinterpret_cast<float*>(smem + 98304);  // [32][128] f32, 16 KB

  const int w = tid >> 6, lane = tid & 63;
  const int wr = w & 1, wc = w >> 1;              // m-tile 0..1, n-32-block 0..3
  const int l15 = lane & 15, lh = lane >> 4;

  // stage own Vw chunk: fp32 -> bf16 -> swizzled LDS (one-time)
  for (int u = tid; u < 2048; u += 512) {         // unit = 8 k-elems of one row
    int n = u >> 4, kc = u & 15;
    const f32x4* src = reinterpret_cast<const f32x4*>(
        Vw + ((size_t)(cid * 128 + n)) * H_ + kc * 8);
    f32x4 a = src[0], b = src[1];
    s16x8 o;
    o[0] = (short)f2bf(a.x); o[1] = (short)f2bf(a.y);
    o[2] = (short)f2bf(a.z); o[3] = (short)f2bf(a.w);
    o[4] = (short)f2bf(b.x); o[5] = (short)f2bf(b.y);
    o[6] = (short)f2bf(b.z); o[7] = (short)f2bf(b.w);
    *reinterpret_cast<s16x8*>(vwo + n * 256 + ((kc * 16) ^ ((n & 7) << 4))) = o;
  }
  // epilogue-read mapping: row r = tid>>4 (batch), 16B-chunk c16 = tid&15
  const int er = tid >> 4, ec = tid & 15;
  const f32x4* Vb4 = reinterpret_cast<const f32x4*>(Vb);
  f32x4 vboL = Vb4[cid * 32 + ec];        // cols ec*4..+3
  f32x4 vboH = Vb4[cid * 32 + 16 + ec];   // cols 64+ec*4..+3
  const int hb_ = tid >> 4, hkc_ = tid & 15;
  const int hswz = hb_ * 256 + ((hkc_ * 16) ^ ((hb_ & 7) << 4));
  __syncthreads();

  for (int win = 0; win < NWIN; ++win) {
    if (tid == 0) {
      while (__hip_atomic_load(&cnt[win], __ATOMIC_RELAXED,
                               __HIP_MEMORY_SCOPE_AGENT) < NB)
        __builtin_amdgcn_s_sleep(8);
      (void)__hip_atomic_load(&cnt[win], __ATOMIC_ACQUIRE,
                              __HIP_MEMORY_SCOPE_AGENT);  // one L1/L2 invalidate
    }
    __syncthreads();

    // prefetch h for this window's step 0
    s16x8 hv = *reinterpret_cast<const s16x8*>(
        hbf + (size_t)(win * WSTEPS) * (NB * H_) + tid * 8);

    // rotating duty chunk staging
    const int k = cid - NX * win;
    const bool duty = (k >= 0) && (k < NX);
    int chunk_x = NCONS + k;
    f32x4 vbxL = {0,0,0,0}, vbxH = {0,0,0,0};
    if (duty) {
      for (int u = tid; u < 2048; u += 512) {
        int n = u >> 4, kc = u & 15;
        const f32x4* src = reinterpret_cast<const f32x4*>(
            Vw + ((size_t)(chunk_x * 128 + n)) * H_ + kc * 8);
        f32x4 a = src[0], b = src[1];
        s16x8 o;
        o[0] = (short)f2bf(a.x); o[1] = (short)f2bf(a.y);
        o[2] = (short)f2bf(a.z); o[3] = (short)f2bf(a.w);
        o[4] = (short)f2bf(b.x); o[5] = (short)f2bf(b.y);
        o[6] = (short)f2bf(b.z); o[7] = (short)f2bf(b.w);
        *reinterpret_cast<s16x8*>(vwx + n * 256 + ((kc * 16) ^ ((n & 7) << 4))) = o;
      }
      vbxL = Vb4[chunk_x * 32 + ec];
      vbxH = Vb4[chunk_x * 32 + 16 + ec];
    }

    for (int tt = 0; tt < WSTEPS; ++tt) {
      const int t = win * WSTEPS + tt;
      unsigned char* hcur = hlb + (tt & 1) * 8192;
      *reinterpret_cast<s16x8*>(hcur + hswz) = hv;   // stage h_t
      bar_lds();  // A: h_t + duty vwx visible; prev-step trbuf reads complete
      if (tt < WSTEPS - 1)
        hv = *reinterpret_cast<const s16x8*>(
            hbf + (size_t)(t + 1) * (NB * H_) + tid * 8);

      s16x8 af[4];
      const int ra = wr * 16 + l15;
#pragma unroll
      for (int kt = 0; kt < 4; ++kt)
        af[kt] = *reinterpret_cast<const s16x8*>(
            hcur + ra * 256 + ((kt * 64 + lh * 16) ^ ((ra & 7) << 4)));

      const int rb = wc * 32 + l15;
      // own chunk -> trO
      {
        f32x4 acc0 = {0.f,0.f,0.f,0.f}, acc1 = acc0;
#pragma unroll
        for (int kt = 0; kt < 4; ++kt) {
          s16x8 b0 = *reinterpret_cast<const s16x8*>(
              vwo + rb * 256 + ((kt * 64 + lh * 16) ^ ((rb & 7) << 4)));
          s16x8 b1 = *reinterpret_cast<const s16x8*>(
              vwo + (rb + 16) * 256 + ((kt * 64 + lh * 16) ^ (((rb + 16) & 7) << 4)));
          acc0 = __builtin_amdgcn_mfma_f32_16x16x32_bf16(af[kt], b0, acc0, 0, 0, 0);
          acc1 = __builtin_amdgcn_mfma_f32_16x16x32_bf16(af[kt], b1, acc1, 0, 0, 0);
        }
#pragma unroll
        for (int i = 0; i < 4; ++i) {
          int b = wr * 16 + lh * 4 + i;
          trO[b * 128 + wc * 32 + l15]      = acc0[i];   // ds_write2 pair
          trO[b * 128 + wc * 32 + 16 + l15] = acc1[i];
        }
      }
      // duty chunk -> trX
      if (duty) {
        f32x4 acc0 = {0.f,0.f,0.f,0.f}, acc1 = acc0;
#pragma unroll
        for (int kt = 0; kt < 4; ++kt) {
          s16x8 b0 = *reinterpret_cast<const s16x8*>(
              vwx + rb * 256 + ((kt * 64 + lh * 16) ^ ((rb & 7) << 4)));
          s16x8 b1 = *reinterpret_cast<const s16x8*>(
              vwx + (rb + 16) * 256 + ((kt * 64 + lh * 16) ^ (((rb + 16) & 7) << 4)));
          acc0 = __builtin_amdgcn_mfma_f32_16x16x32_bf16(af[kt], b0, acc0, 0, 0, 0);
          acc1 = __builtin_amdgcn_mfma_f32_16x16x32_bf16(af[kt], b1, acc1, 0, 0, 0);
        }
#pragma unroll
        for (int i = 0; i < 4; ++i) {
          int b = wr * 16 + lh * 4 + i;
          trX[b * 128 + wc * 32 + l15]      = acc0[i];
          trX[b * 128 + wc * 32 + 16 + l15] = acc1[i];
        }
      }
      bar_lds();  // B: transpose buffers visible

      // epilogue: full-line stores. Thread (er,ec): row er, 16 lanes cover
      // 64 contiguous floats per store inst = 256 B full-line segments.
      {
        f32x4 lo = *reinterpret_cast<const f32x4*>(trO + er * 128 + ec * 4);
        f32x4 hi = *reinterpret_cast<const f32x4*>(trO + er * 128 + 64 + ec * 4);
        float* orow = out + ((size_t)er * NT + t) * V_ + cid * 128;
        *reinterpret_cast<f32x4*>(orow + ec * 4)      = lo + vboL;
        *reinterpret_cast<f32x4*>(orow + 64 + ec * 4) = hi + vboH;
      }
      if (duty) {
        f32x4 lo = *reinterpret_cast<const f32x4*>(trX + er * 128 + ec * 4);
        f32x4 hi = *reinterpret_cast<const f32x4*>(trX + er * 128 + 64 + ec * 4);
        float* orow = out + ((size_t)er * NT + t) * V_ + chunk_x * 128;
        *reinterpret_cast<f32x4*>(orow + ec * 4)      = lo + vbxL;
        *reinterpret_cast<f32x4*>(orow + 64 + ec * 4) = hi + vbxH;
      }
    }
  }
}

// ---------------------------------------------------------------------------
extern "C" void kernel_launch(void* const* d_in, const int* in_sizes, int n_in,
                              void* d_out, int out_size, void* d_ws, size_t ws_size,
                              hipStream_t stream) {
  const float* x   = (const float*)d_in[0];
  const float* Wf  = (const float*)d_in[1];
  const float* bWf = (const float*)d_in[2];
  const float* Uf  = (const float*)d_in[3];
  const float* bUf = (const float*)d_in[4];
  const float* Wi  = (const float*)d_in[5];
  const float* bWi = (const float*)d_in[6];
  const float* Ui  = (const float*)d_in[7];
  const float* bUi = (const float*)d_in[8];
  const float* Wc  = (const float*)d_in[9];
  const float* bWc = (const float*)d_in[10];
  const float* Uc  = (const float*)d_in[11];
  const float* bUc = (const float*)d_in[12];
  const float* Wo  = (const float*)d_in[13];
  const float* bWo = (const float*)d_in[14];
  const float* Uo  = (const float*)d_in[15];
  const float* bUo = (const float*)d_in[16];
  const float* Vw  = (const float*)d_in[17];
  const float* Vb  = (const float*)d_in[18];
  float* out = (float*)d_out;

  unsigned short* hbf = (unsigned short*)d_ws;                 // 1 MB [t][b][H]
  int* cnt = (int*)((char*)d_ws + (1u << 20));                 // 32 B
  float* hlast = out + (size_t)NB * NT * V_;

  hipLaunchKernelGGL(zero_cnt, dim3(1), dim3(64), 0, stream, cnt);
  hipLaunchKernelGGL(lstm_fused, dim3(256), dim3(512), 0, stream,
                     x, Wf, bWf, Uf, bUf, Wi, bWi, Ui, bUi, Wc, bWc, Uc, bUc,
                     Wo, bWo, Uo, bUo, Vw, Vb, hbf, cnt, out, hlast);
}

// Round 12
// 155.663 us; speedup vs baseline: 1.2120x; 1.2120x over previous
//
#include <hip/hip_runtime.h>
#include <stdint.h>
#include <stddef.h>
#include <math.h>

#define E_ 32
#define H_ 128
#define V_ 32000
#define NB 32
#define NT 128
#define NCONS 224      // consumer blocks (bid 32..255)
#define NCHUNK 250     // 128-col vocab chunks; 224 owned + 26 rotating extras
#define NX (NCHUNK - NCONS)   // 26 extra chunks
#define WSTEPS 16      // pipeline window (steps per release)
#define NWIN (NT / WSTEPS)    // 8 windows

typedef float f32x4 __attribute__((ext_vector_type(4)));
typedef short s16x8 __attribute__((ext_vector_type(8)));

__device__ inline unsigned short f2bf(float f) {
  uint32_t u = __float_as_uint(f);
  return (unsigned short)((u + 0x7FFFu + ((u >> 16) & 1u)) >> 16);
}

__device__ inline float dpp_xor1(float v) {   // lane l <- lane l^1 (quad_perm)
  return __int_as_float(__builtin_amdgcn_update_dpp(
      0, __float_as_int(v), 0xB1, 0xF, 0xF, true));
}
__device__ inline float dpp_xor2(float v) {   // lane l <- lane l^2
  return __int_as_float(__builtin_amdgcn_update_dpp(
      0, __float_as_int(v), 0x4E, 0xF, 0xF, true));
}

__global__ void zero_cnt(int* cnt) {
  if (threadIdx.x < NWIN) cnt[threadIdx.x] = 0;
}

// Fused producer-consumer, grid 256 x 512 (1 block/CU, all co-resident).
// R10 structure (measured 166.3us) with ONE change: consumer B-fragments
// (Vw, constant across all steps) hoisted from per-step LDS reads into
// registers — per-step LDS issue drops from 12 to 4 ds_read_b128/thread.
__global__ __launch_bounds__(512, 1)
void lstm_fused(const float* __restrict__ x,
                const float* __restrict__ Wf, const float* __restrict__ bWf,
                const float* __restrict__ Uf, const float* __restrict__ bUf,
                const float* __restrict__ Wi, const float* __restrict__ bWi,
                const float* __restrict__ Ui, const float* __restrict__ bUi,
                const float* __restrict__ Wc, const float* __restrict__ bWc,
                const float* __restrict__ Uc, const float* __restrict__ bUc,
                const float* __restrict__ Wo, const float* __restrict__ bWo,
                const float* __restrict__ Uo, const float* __restrict__ bUo,
                const float* __restrict__ Vw, const float* __restrict__ Vb,
                unsigned short* __restrict__ hbf,  // [NT][NB][H_] bf16 bits
                int* __restrict__ cnt,             // [NWIN] window counters
                float* __restrict__ out,           // [NB][NT][V_]
                float* __restrict__ hlast)         // [NB][H_]
{
  __shared__ __align__(16) unsigned char smem[81920];
  const int bid = blockIdx.x;
  const int tid = threadIdx.x;

  if (bid < NB) {
    // ---------------- producer: recurrence for batch `bid` (R10 verbatim) ---
    float* xs = reinterpret_cast<float*>(smem);            // [NT][E_] 16 KB
    float* hd = reinterpret_cast<float*>(smem + 16384);    // [2][144] padded h

    const int q  = tid & 3;    // k-quarter
    const int jj = tid >> 2;   // output index 0..127

    const float* WL[4]  = {Wf, Wi, Wc, Wo};
    const float* UL[4]  = {Uf, Ui, Uc, Uo};
    const float* bWL[4] = {bWf, bWi, bWc, bWo};
    const float* bUL[4] = {bUf, bUi, bUc, bUo};

    f32x4 wr_[4][2];  // W[g][jj, 8q..8q+8)
    f32x4 ur_[4][8];  // U[g][jj, 32q..32q+32)  -- 160 VGPRs, MUST NOT SPILL
    float bias_[4];
#pragma unroll
    for (int g = 0; g < 4; ++g) {
      const f32x4* Wp = reinterpret_cast<const f32x4*>(WL[g] + jj * E_ + q * 8);
      wr_[g][0] = Wp[0]; wr_[g][1] = Wp[1];
      const f32x4* Up = reinterpret_cast<const f32x4*>(UL[g] + jj * H_ + q * 32);
#pragma unroll
      for (int r = 0; r < 8; ++r) ur_[g][r] = Up[r];
      bias_[g] = bWL[g][jj] + bUL[g][jj];
    }

    for (int i = tid; i < NT * E_; i += 512) xs[i] = x[bid * (NT * E_) + i];
    if (tid < 144) hd[tid] = 0.f;
    float creg = 0.f;
    __syncthreads();

    for (int t = 0; t < NT; ++t) {
      const int cur = t & 1, nxt = cur ^ 1;
      const f32x4* hq = reinterpret_cast<const f32x4*>(hd + cur * 144 + q * 36);
      const f32x4* xq = reinterpret_cast<const f32x4*>(xs + t * E_ + q * 8);

      f32x4 p0 = {0.f,0.f,0.f,0.f}, p1 = p0, p2 = p0, p3 = p0;
#pragma unroll
      for (int r = 0; r < 2; ++r) {
        f32x4 xv = xq[r];
        p0 += wr_[0][r] * xv; p1 += wr_[1][r] * xv;
        p2 += wr_[2][r] * xv; p3 += wr_[3][r] * xv;
      }
#pragma unroll
      for (int r = 0; r < 8; ++r) {
        f32x4 hv = hq[r];
        p0 += ur_[0][r] * hv; p1 += ur_[1][r] * hv;
        p2 += ur_[2][r] * hv; p3 += ur_[3][r] * hv;
      }
      float s0 = (p0.x + p0.y) + (p0.z + p0.w);
      float s1 = (p1.x + p1.y) + (p1.z + p1.w);
      float s2 = (p2.x + p2.y) + (p2.z + p2.w);
      float s3 = (p3.x + p3.y) + (p3.z + p3.w);
      s0 += dpp_xor1(s0); s0 += dpp_xor2(s0);
      s1 += dpp_xor1(s1); s1 += dpp_xor2(s1);
      s2 += dpp_xor1(s2); s2 += dpp_xor2(s2);
      s3 += dpp_xor1(s3); s3 += dpp_xor2(s3);
      s0 += bias_[0]; s1 += bias_[1]; s2 += bias_[2]; s3 += bias_[3];

      float own = (q == 0) ? s0 : (q == 1) ? s1 : (q == 2) ? s2 : s3;
      float xin = (q == 2) ? own + own : own;
      float val = __builtin_amdgcn_rcpf(1.f + __expf(-xin));
      if (q == 2) val = 2.f * val - 1.f;
      float v1 = dpp_xor1(val);
      float v2 = dpp_xor2(val);
      float v3 = dpp_xor2(v1);
      float f_ = (q == 0) ? val : (q == 1) ? v1 : (q == 2) ? v2 : v3;
      float i_ = (q == 0) ? v1 : (q == 1) ? val : (q == 2) ? v3 : v2;
      float c_ = (q == 0) ? v2 : (q == 1) ? v3 : (q == 2) ? val : v1;
      float o_ = (q == 0) ? v3 : (q == 1) ? v2 : (q == 2) ? v1 : val;

      float cn = f_ * creg + i_ * c_;
      creg = cn;
      float hn = o_ * (2.f * __builtin_amdgcn_rcpf(1.f + __expf(-2.f * cn)) - 1.f);

      if (q == 0) {
        hd[nxt * 144 + jj + ((jj >> 5) << 2)] = hn;
        hbf[((size_t)t * NB + bid) * H_ + jj] = f2bf(hn);  // [t][b][H]
        if (t == NT - 1) hlast[bid * H_ + jj] = hn;
      }
      __syncthreads();
      if ((t & (WSTEPS - 1)) == (WSTEPS - 1) && tid == 0)
        __hip_atomic_fetch_add(&cnt[t / WSTEPS], 1, __ATOMIC_RELEASE,
                               __HIP_MEMORY_SCOPE_AGENT);
    }
    return;
  }

  // ---------------- consumer: own chunk + rotating duty chunk ----------------
  const int cid = bid - NB;                       // 0..223, owns chunk `cid`
  unsigned char* vwo = smem;                      // own  Vw [128][256 B] swizzled
  unsigned char* vwx = smem + 32768;              // duty Vw [128][256 B] swizzled
  unsigned char* hlb = smem + 65536;              // [2][32 rows][256 B] swizzled

  const int w = tid >> 6, lane = tid & 63;
  const int wr = w & 1, wc = w >> 1;              // m-tile 0..1, n-32-block 0..3
  const int l15 = lane & 15, lh = lane >> 4;

  // stage own Vw chunk: fp32 -> bf16 -> swizzled LDS (one-time)
  for (int u = tid; u < 2048; u += 512) {         // unit = 8 k-elems of one row
    int n = u >> 4, kc = u & 15;
    const f32x4* src = reinterpret_cast<const f32x4*>(
        Vw + ((size_t)(cid * 128 + n)) * H_ + kc * 8);
    f32x4 a = src[0], b = src[1];
    s16x8 o;
    o[0] = (short)f2bf(a.x); o[1] = (short)f2bf(a.y);
    o[2] = (short)f2bf(a.z); o[3] = (short)f2bf(a.w);
    o[4] = (short)f2bf(b.x); o[5] = (short)f2bf(b.y);
    o[6] = (short)f2bf(b.z); o[7] = (short)f2bf(b.w);
    *reinterpret_cast<s16x8*>(vwo + n * 256 + ((kc * 16) ^ ((n & 7) << 4))) = o;
  }
  float vbo0 = Vb[cid * 128 + wc * 32 + l15];
  float vbo1 = Vb[cid * 128 + wc * 32 + 16 + l15];
  const int hb_ = tid >> 4, hkc_ = tid & 15;      // h-stage LDS slot for this thread
  const int hswz = hb_ * 256 + ((hkc_ * 16) ^ ((hb_ & 7) << 4));
  __syncthreads();

  // hoist OWN B-fragments into registers (constant over all 128 steps):
  // 8 x s16x8 = 32 VGPRs; removes 8 of 12 per-step ds_read_b128.
  const int rb = wc * 32 + l15;
  s16x8 bO0[4], bO1[4];
#pragma unroll
  for (int kt = 0; kt < 4; ++kt) {
    bO0[kt] = *reinterpret_cast<const s16x8*>(
        vwo + rb * 256 + ((kt * 64 + lh * 16) ^ ((rb & 7) << 4)));
    bO1[kt] = *reinterpret_cast<const s16x8*>(
        vwo + (rb + 16) * 256 + ((kt * 64 + lh * 16) ^ (((rb + 16) & 7) << 4)));
  }

  s16x8 bX0[4], bX1[4];   // duty B-fragments, loaded once in the duty window
  float vbx0 = 0.f, vbx1 = 0.f;

  for (int win = 0; win < NWIN; ++win) {
    if (tid == 0) {
      while (__hip_atomic_load(&cnt[win], __ATOMIC_RELAXED,
                               __HIP_MEMORY_SCOPE_AGENT) < NB)
        __builtin_amdgcn_s_sleep(8);
      (void)__hip_atomic_load(&cnt[win], __ATOMIC_ACQUIRE,
                              __HIP_MEMORY_SCOPE_AGENT);  // one L1/L2 invalidate
    }
    __syncthreads();

    // prefetch h for this window's step 0 (drains under duty staging)
    s16x8 hv = *reinterpret_cast<const s16x8*>(
        hbf + (size_t)(win * WSTEPS) * (NB * H_) + tid * 8);

    // rotating duty: in window `win`, blocks 26*win .. 26*win+25 stage one
    // extra chunk each. Every (chunk,window) covered exactly once.
    const int k = cid - NX * win;
    const bool duty = (k >= 0) && (k < NX);
    int chunk_x = NCONS + k;
    if (duty) {
      for (int u = tid; u < 2048; u += 512) {
        int n = u >> 4, kc = u & 15;
        const f32x4* src = reinterpret_cast<const f32x4*>(
            Vw + ((size_t)(chunk_x * 128 + n)) * H_ + kc * 8);
        f32x4 a = src[0], b = src[1];
        s16x8 o;
        o[0] = (short)f2bf(a.x); o[1] = (short)f2bf(a.y);
        o[2] = (short)f2bf(a.z); o[3] = (short)f2bf(a.w);
        o[4] = (short)f2bf(b.x); o[5] = (short)f2bf(b.y);
        o[6] = (short)f2bf(b.z); o[7] = (short)f2bf(b.w);
        *reinterpret_cast<s16x8*>(vwx + n * 256 + ((kc * 16) ^ ((n & 7) << 4))) = o;
      }
      vbx0 = Vb[chunk_x * 128 + wc * 32 + l15];
      vbx1 = Vb[chunk_x * 128 + wc * 32 + 16 + l15];
    }
    // duty ds_writes become visible at step 0's post-stage barrier; duty
    // B-fragments are pulled into registers there (tt==0) and reused.

    for (int tt = 0; tt < WSTEPS; ++tt) {
      const int t = win * WSTEPS + tt;
      unsigned char* hcur = hlb + (tt & 1) * 8192;
      // write prefetched h_t to LDS, then immediately issue the load for t+1
      *reinterpret_cast<s16x8*>(hcur + hswz) = hv;
      if (tt < WSTEPS - 1)
        hv = *reinterpret_cast<const s16x8*>(
            hbf + (size_t)(t + 1) * (NB * H_) + tid * 8);
      __syncthreads();

      if (tt == 0 && duty) {
#pragma unroll
        for (int kt = 0; kt < 4; ++kt) {
          bX0[kt] = *reinterpret_cast<const s16x8*>(
              vwx + rb * 256 + ((kt * 64 + lh * 16) ^ ((rb & 7) << 4)));
          bX1[kt] = *reinterpret_cast<const s16x8*>(
              vwx + (rb + 16) * 256 + ((kt * 64 + lh * 16) ^ (((rb + 16) & 7) << 4)));
        }
      }

      s16x8 af[4];
      const int ra = wr * 16 + l15;
#pragma unroll
      for (int kt = 0; kt < 4; ++kt)
        af[kt] = *reinterpret_cast<const s16x8*>(
            hcur + ra * 256 + ((kt * 64 + lh * 16) ^ ((ra & 7) << 4)));

      // own chunk (B from registers)
      {
        f32x4 acc0 = {0.f,0.f,0.f,0.f}, acc1 = acc0;
#pragma unroll
        for (int kt = 0; kt < 4; ++kt) {
          acc0 = __builtin_amdgcn_mfma_f32_16x16x32_bf16(af[kt], bO0[kt], acc0, 0, 0, 0);
          acc1 = __builtin_amdgcn_mfma_f32_16x16x32_bf16(af[kt], bO1[kt], acc1, 0, 0, 0);
        }
        const int colbase = cid * 128 + wc * 32;
#pragma unroll
        for (int i = 0; i < 4; ++i) {
          int b = wr * 16 + lh * 4 + i;
          float* orow = out + ((size_t)b * NT + t) * V_ + colbase;
          orow[l15]      = acc0[i] + vbo0;
          orow[16 + l15] = acc1[i] + vbo1;
        }
      }
      // duty chunk (B from registers)
      if (duty) {
        f32x4 acc0 = {0.f,0.f,0.f,0.f}, acc1 = acc0;
#pragma unroll
        for (int kt = 0; kt < 4; ++kt) {
          acc0 = __builtin_amdgcn_mfma_f32_16x16x32_bf16(af[kt], bX0[kt], acc0, 0, 0, 0);
          acc1 = __builtin_amdgcn_mfma_f32_16x16x32_bf16(af[kt], bX1[kt], acc1, 0, 0, 0);
        }
        const int colbase = chunk_x * 128 + wc * 32;
#pragma unroll
        for (int i = 0; i < 4; ++i) {
          int b = wr * 16 + lh * 4 + i;
          float* orow = out + ((size_t)b * NT + t) * V_ + colbase;
          orow[l15]      = acc0[i] + vbx0;
          orow[16 + l15] = acc1[i] + vbx1;
        }
      }
    }
  }
}

// ---------------------------------------------------------------------------
extern "C" void kernel_launch(void* const* d_in, const int* in_sizes, int n_in,
                              void* d_out, int out_size, void* d_ws, size_t ws_size,
                              hipStream_t stream) {
  const float* x   = (const float*)d_in[0];
  const float* Wf  = (const float*)d_in[1];
  const float* bWf = (const float*)d_in[2];
  const float* Uf  = (const float*)d_in[3];
  const float* bUf = (const float*)d_in[4];
  const float* Wi  = (const float*)d_in[5];
  const float* bWi = (const float*)d_in[6];
  const float* Ui  = (const float*)d_in[7];
  const float* bUi = (const float*)d_in[8];
  const float* Wc  = (const float*)d_in[9];
  const float* bWc = (const float*)d_in[10];
  const float* Uc  = (const float*)d_in[11];
  const float* bUc = (const float*)d_in[12];
  const float* Wo  = (const float*)d_in[13];
  const float* bWo = (const float*)d_in[14];
  const float* Uo  = (const float*)d_in[15];
  const float* bUo = (const float*)d_in[16];
  const float* Vw  = (const float*)d_in[17];
  const float* Vb  = (const float*)d_in[18];
  float* out = (float*)d_out;

  unsigned short* hbf = (unsigned short*)d_ws;                 // 1 MB [t][b][H]
  int* cnt = (int*)((char*)d_ws + (1u << 20));                 // 32 B
  float* hlast = out + (size_t)NB * NT * V_;

  hipLaunchKernelGGL(zero_cnt, dim3(1), dim3(64), 0, stream, cnt);
  hipLaunchKernelGGL(lstm_fused, dim3(256), dim3(512), 0, stream,
                     x, Wf, bWf, Uf, bUf, Wi, bWi, Ui, bUi, Wc, bWc, Uc, bUc,
                     Wo, bWo, Uo, bUo, Vw, Vb, hbf, cnt, out, hlast);
}